// Round 2
// baseline (322.095 us; speedup 1.0000x reference)
//
#include <hip/hip_runtime.h>
#include <hip/hip_fp16.h>

#define N_NODES 50000
#define N_EDGES 800000
#define N_GRAPHS 256
#define F_IN 112
#define DIM 32
#define BN_EPS 1e-5
#define HROW 128   // fp16 row stride (256 B = exactly 2 lines, zero waste)
#define CAP 64     // edge slots per node (P(deg>63) ~ 1e-19 for Poisson(16))
#define CB 391     // coarse buckets of 128 nodes (ceil(50000/128))
#define CBCAP 2560 // entries per coarse bucket (Poisson(2046) + 11 sigma)
#define CHUNK 8192 // edges per partition block
#define NPART 98   // ceil(800000/8192)
#define GEMM_MB 782 // ceil(50000/64)

typedef __attribute__((ext_vector_type(8))) _Float16 half8;
typedef __attribute__((ext_vector_type(4))) float float4v;

// ---- fp16 split helpers ----
__device__ inline unsigned short f2h_u(float f) {
    union { __half h; unsigned short u; } v; v.h = __float2half(f); return v.u;
}
__device__ inline float h2f_u(unsigned short u) {
    union { unsigned short u; __half h; } v; v.u = u; return __half2float(v.h);
}

// W[KxN] fp32 -> hi/lo fp16 [N][Kpad] (transposed, zero-padded)
__device__ inline void w_split_body(const float* __restrict__ W, int K, int N, int Kpad,
                                    unsigned short* __restrict__ hi_t,
                                    unsigned short* __restrict__ lo_t, int idx) {
    if (idx >= N * Kpad) return;
    int n = idx / Kpad, k = idx - n * Kpad;
    float v = (k < K) ? W[(size_t)k * N + n] : 0.f;
    unsigned short h = f2h_u(v);
    hi_t[idx] = h;
    lo_t[idx] = f2h_u(v - h2f_u(h));
}

// ---- MERGED build kernel: edge partition (blocks 0..NPART-1) + prep work
#define MB_P  NPART
#define MB_XH (MB_P + 3125)   // 50000*64 half2 / 1024
#define MB_W1 (MB_XH + 14)    // 112*128 / 1024
#define MB_W2 (MB_W1 + 14)
#define MB_W4 (MB_W2 + 1)
#define MB_GB (MB_W4 + 49)    // ceil(50000/1024)
__global__ __launch_bounds__(1024) void build_kernel(
        const int* __restrict__ src, const int* __restrict__ dst,
        int* __restrict__ gcur,     // [CB], zeroed
        int* __restrict__ bucket,   // [CB][CBCAP]
        const float* __restrict__ X, __half* __restrict__ Xh,
        const float* __restrict__ g1_w1, unsigned short* w1h, unsigned short* w1l,
        const float* __restrict__ g1_w2, unsigned short* w2h, unsigned short* w2l,
        const float* __restrict__ g2_w2, unsigned short* w4h, unsigned short* w4l,
        const int* __restrict__ batch, int* __restrict__ goff) {
    int b = blockIdx.x;
    int t = threadIdx.x;
    if (b < MB_P) {
        __shared__ int hist[512];
        __shared__ int lofs[512];
        __shared__ int lcur[512];
        __shared__ int gbase[512];
        __shared__ int staging[CHUNK];
        int base = b * CHUNK;
        int total = min(CHUNK, N_EDGES - base);
        for (int i = t; i < 512; i += 1024) hist[i] = 0;
        __syncthreads();
        int d[8], s[8];
#pragma unroll
        for (int j = 0; j < 8; j++) {
            int i = base + j * 1024 + t;
            if (i < N_EDGES) {
                d[j] = __builtin_nontemporal_load(dst + i);
                s[j] = __builtin_nontemporal_load(src + i);
            } else {
                d[j] = -1;
            }
        }
#pragma unroll
        for (int j = 0; j < 8; j++) {
            if (d[j] >= 0) atomicAdd(&hist[d[j] >> 7], 1);
        }
        __syncthreads();
        if (t < 512) lofs[t] = hist[t];
        __syncthreads();
        for (int o = 1; o < 512; o <<= 1) {
            int add = (t < 512 && t >= o) ? lofs[t - o] : 0;
            __syncthreads();
            if (t < 512) lofs[t] += add;
            __syncthreads();
        }
        if (t < CB) {
            gbase[t] = (hist[t] > 0) ? atomicAdd(&gcur[t], hist[t]) : 0;
        }
        if (t < 512) lcur[t] = lofs[t] - hist[t];
        __syncthreads();
#pragma unroll
        for (int j = 0; j < 8; j++) {
            if (d[j] >= 0) {
                int bb = d[j] >> 7;
                int p = atomicAdd(&lcur[bb], 1);
                staging[p] = (d[j] << 16) | s[j];
            }
        }
        __syncthreads();
        for (int p = t; p < total; p += 1024) {
            int e = staging[p];
            int bb = ((unsigned)e >> 16) >> 7;
            int ls = lofs[bb] - hist[bb];
            int di = gbase[bb] + (p - ls);
            if (di < CBCAP) bucket[(size_t)bb * CBCAP + di] = e;
        }
    } else if (b < MB_XH) {
        int idx = (b - MB_P) * 1024 + t;
        if (idx >= N_NODES * (HROW / 2)) return;
        int row = idx / (HROW / 2), c2 = idx - row * (HROW / 2);
        int col = c2 * 2;
        float2 v = make_float2(0.f, 0.f);
        if (col < F_IN) v = *(const float2*)(X + (size_t)row * F_IN + col);
        ((__half2*)Xh)[idx] = __floats2half2_rn(v.x, v.y);
    } else if (b < MB_W1) {
        w_split_body(g1_w1, F_IN, F_IN, 128, w1h, w1l, (b - MB_XH) * 1024 + t);
    } else if (b < MB_W2) {
        w_split_body(g1_w2, F_IN, F_IN, 128, w2h, w2l, (b - MB_W1) * 1024 + t);
    } else if (b < MB_W4) {
        w_split_body(g2_w2, DIM, DIM, 32, w4h, w4l, (b - MB_W2) * 1024 + t);
    } else {
        int i = (b - MB_W4) * 1024 + t;
        if (i >= N_NODES) return;
        int cur = batch[i];
        int prev = (i == 0) ? -1 : batch[i - 1];
        for (int g = prev + 1; g <= cur; g++) goff[g] = i;
        if (i == N_NODES - 1) {
            for (int g = cur + 1; g <= N_GRAPHS; g++) goff[g] = N_NODES;
        }
    }
}

// ---- bin_build: one block per 128-node coarse bucket -> perm/deg coalesced
__global__ __launch_bounds__(1024) void bin_build(const int* __restrict__ gcur,
                                                  const int* __restrict__ bucket,
                                                  unsigned short* __restrict__ perm_pad,
                                                  int* __restrict__ deg) {
    __shared__ __align__(16) unsigned short bins[128][CAP];   // 16 KB
    __shared__ int lcur[128];
    int b = blockIdx.x, t = threadIdx.x;
    if (t < 128) lcur[t] = 0;
    __syncthreads();
    int count = min(gcur[b], CBCAP);
    for (int i = t; i < count; i += 1024) {
        int e = bucket[(size_t)b * CBCAP + i];
        int l = ((unsigned)e >> 16) & 127;
        int s = e & 0xFFFF;
        int c = atomicAdd(&lcur[l], 1);
        if (c < CAP) bins[l][c] = (unsigned short)s;
    }
    __syncthreads();
    if (t < 128) {
        int node = b * 128 + t;
        if (node < N_NODES) deg[node] = min(lcur[t], CAP);
    }
    for (int i = t; i < 128 * (CAP / 8); i += 1024) {
        int l = i >> 3, q = i & 7;
        int node = b * 128 + l;
        if (node < N_NODES) {
            ((int4*)&perm_pad[(size_t)node * CAP])[q] = ((const int4*)bins[l])[q];
        }
    }
}

// ------- FUSED GIN layer 1: per-block gather (agg) into LDS A-tile, then
// H1 = relu(relu(A@W1+b1)@W2+b2) + BN1 partial stats. Kills the aggA
// 25.6 MB round-trip and hides W staging under the gather.
__global__ __launch_bounds__(256) void gin1_fused(const float* __restrict__ X,
        const __half* __restrict__ Xh,
        const int* __restrict__ deg_arr,
        const unsigned short* __restrict__ perm_pad,
        const unsigned short* __restrict__ W1h, const unsigned short* __restrict__ W1l,
        const float* __restrict__ b1,
        const unsigned short* __restrict__ W2h, const unsigned short* __restrict__ W2l,
        const float* __restrict__ b2,
        __half* __restrict__ Ch, float* __restrict__ pbuf, int M) {
    constexpr int NT = 7, N = 112, Kpad = 128, TS = 136, AS = 136;
    __shared__ __align__(16) unsigned short Afull[64 * AS];  // 17 KB (aliased as sls later)
    __shared__ __align__(16) unsigned short T1[64 * TS];     // 17 KB
    __shared__ __align__(16) unsigned short Wh[N * 32];
    __shared__ __align__(16) unsigned short Wl[N * 32];
    float* sls = (float*)Afull;
    int t = threadIdx.x;
    int lane = t & 63, wid = t >> 6;
    int r0 = blockIdx.x * 64;
    int m = lane & 15, quad = lane >> 4;

    // pre-stage W1 chunk 0 (completes under the gather)
    for (int idx = t; idx < N * 8; idx += 256) {
        int n = idx >> 3, w = idx & 7;
        int gsrc = n * (Kpad / 4) + w;
        ((uint2*)Wh)[idx] = ((const uint2*)W1h)[gsrc];
        ((uint2*)Wl)[idx] = ((const uint2*)W1l)[gsrc];
    }

    // ---- gather phase: wave wid builds A rows wid*16 .. wid*16+15
    for (int i = 0; i < 16; i++) {
        int row = wid * 16 + i;
        int grow = r0 + row;
        float ax = 0.f, ay = 0.f;
        if (grow < M) {
            int deg = deg_arr[grow];
            const unsigned short* pl = perm_pad + (size_t)grow * CAP;
            int e = 0;
            for (; e + 16 <= deg; e += 16) {
                int s[16];
#pragma unroll
                for (int j = 0; j < 16; j++) s[j] = pl[e + j];
                float2 v[16];
#pragma unroll
                for (int j = 0; j < 16; j++)
                    v[j] = __half22float2(*(const __half2*)(Xh + (size_t)s[j] * HROW + 2 * lane));
#pragma unroll
                for (int j = 0; j < 16; j++) { ax += v[j].x; ay += v[j].y; }
            }
            for (; e + 4 <= deg; e += 4) {
                int s0 = pl[e], s1 = pl[e + 1], s2 = pl[e + 2], s3 = pl[e + 3];
                float2 v0 = __half22float2(*(const __half2*)(Xh + (size_t)s0 * HROW + 2 * lane));
                float2 v1 = __half22float2(*(const __half2*)(Xh + (size_t)s1 * HROW + 2 * lane));
                float2 v2 = __half22float2(*(const __half2*)(Xh + (size_t)s2 * HROW + 2 * lane));
                float2 v3 = __half22float2(*(const __half2*)(Xh + (size_t)s3 * HROW + 2 * lane));
                ax += (v0.x + v1.x) + (v2.x + v3.x);
                ay += (v0.y + v1.y) + (v2.y + v3.y);
            }
            for (; e < deg; e++) {
                int s = pl[e];
                float2 v = __half22float2(*(const __half2*)(Xh + (size_t)s * HROW + 2 * lane));
                ax += v.x;
                ay += v.y;
            }
            if (lane < F_IN / 2) {
                float2 self = *(const float2*)(X + (size_t)grow * F_IN + 2 * lane);
                ax += self.x;
                ay += self.y;
            }
        }
        ((__half2*)&Afull[row * AS])[lane] = __floats2half2_rn(ax, ay);
    }
    // T1 pad columns zero
    for (int i = t; i < 64 * 16; i += 256) {
        T1[(i >> 4) * TS + 112 + (i & 15)] = 0;
    }

    float4v acc[NT];
#pragma unroll
    for (int nt = 0; nt < NT; nt++) acc[nt] = (float4v){0.f, 0.f, 0.f, 0.f};

    // ---- phase 1: T = relu(A@W1+b1), A from LDS
    for (int c = 0; c < 4; c++) {
        int kc = c * 32;
        if (c > 0) {
            for (int idx = t; idx < N * 8; idx += 256) {
                int n = idx >> 3, w = idx & 7;
                int gsrc = n * (Kpad / 4) + (kc >> 2) + w;
                ((uint2*)Wh)[idx] = ((const uint2*)W1h)[gsrc];
                ((uint2*)Wl)[idx] = ((const uint2*)W1l)[gsrc];
            }
        }
        __syncthreads();
        half8 a = *(const half8*)&Afull[(wid * 16 + m) * AS + kc + quad * 8];
#pragma unroll
        for (int nt = 0; nt < NT; nt++) {
            half8 b_h = *(const half8*)&Wh[(nt * 16 + m) * 32 + quad * 8];
            half8 b_l = *(const half8*)&Wl[(nt * 16 + m) * 32 + quad * 8];
            acc[nt] = __builtin_amdgcn_mfma_f32_16x16x32_f16(a, b_h, acc[nt], 0, 0, 0);
            acc[nt] = __builtin_amdgcn_mfma_f32_16x16x32_f16(a, b_l, acc[nt], 0, 0, 0);
        }
        __syncthreads();
    }

#pragma unroll
    for (int nt = 0; nt < NT; nt++) {
        int col = nt * 16 + m;
        float bb = b1[col];
#pragma unroll
        for (int r = 0; r < 4; r++) {
            int row = wid * 16 + quad * 4 + r;
            T1[row * TS + col] = f2h_u(fmaxf(acc[nt][r] + bb, 0.f));
        }
        acc[nt] = (float4v){0.f, 0.f, 0.f, 0.f};
    }
    __syncthreads();

    // ---- phase 2: H1 = relu(T@W2+b2)
    for (int c = 0; c < 4; c++) {
        int kc = c * 32;
        for (int idx = t; idx < N * 8; idx += 256) {
            int n = idx >> 3, w = idx & 7;
            int gsrc = n * (Kpad / 4) + (kc >> 2) + w;
            ((uint2*)Wh)[idx] = ((const uint2*)W2h)[gsrc];
            ((uint2*)Wl)[idx] = ((const uint2*)W2l)[gsrc];
        }
        __syncthreads();
        half8 a = *(const half8*)&T1[(wid * 16 + m) * TS + kc + quad * 8];
#pragma unroll
        for (int nt = 0; nt < NT; nt++) {
            half8 b_h = *(const half8*)&Wh[(nt * 16 + m) * 32 + quad * 8];
            half8 b_l = *(const half8*)&Wl[(nt * 16 + m) * 32 + quad * 8];
            acc[nt] = __builtin_amdgcn_mfma_f32_16x16x32_f16(a, b_h, acc[nt], 0, 0, 0);
            acc[nt] = __builtin_amdgcn_mfma_f32_16x16x32_f16(a, b_l, acc[nt], 0, 0, 0);
        }
        __syncthreads();
    }

    float st_s[NT], st_q[NT];
#pragma unroll
    for (int nt = 0; nt < NT; nt++) {
        int col = nt * 16 + m;
        float bb = b2[col];
        float s_loc = 0.f, q_loc = 0.f;
#pragma unroll
        for (int r = 0; r < 4; r++) {
            int row = r0 + wid * 16 + quad * 4 + r;
            float v = fmaxf(acc[nt][r] + bb, 0.f);
            if (row < M) {
                Ch[(size_t)row * HROW + col] = __float2half(v);
                s_loc += v;
                q_loc += v * v;
            }
        }
        st_s[nt] = s_loc;
        st_q[nt] = q_loc;
    }
    for (int i = t; i < 64 * 2; i += 256) {
        int row = r0 + (i >> 1), o = (i & 1) * 8;
        if (row < M) *(uint4*)((unsigned short*)Ch + (size_t)row * HROW + 112 + o) = make_uint4(0, 0, 0, 0);
    }
#pragma unroll
    for (int nt = 0; nt < NT; nt++) {
        float s = st_s[nt], q = st_q[nt];
        s += __shfl_xor(s, 16); s += __shfl_xor(s, 32);
        q += __shfl_xor(q, 16); q += __shfl_xor(q, 32);
        if (quad == 0) {
            sls[wid * 2 * N + nt * 16 + m] = s;
            sls[wid * 2 * N + N + nt * 16 + m] = q;
        }
    }
    __syncthreads();
    for (int j = t; j < 2 * N; j += 256) {
        pbuf[(size_t)blockIdx.x * 2 * N + j] = sls[0 * 2 * N + j] + sls[1 * 2 * N + j] +
                                               sls[2 * 2 * N + j] + sls[3 * 2 * N + j];
    }
}

// ------- MERGED BN1 finalize + W3 fold: block j = feature j. Computes
// s1_j/t1_j from pbuf, writes the 32 folded W3 entries for k=j, atomically
// accumulates c0[n] += t1_j * W[j][n]. (w3 pad rows k>=112 zeroed by memset.)
__global__ __launch_bounds__(256) void bn1_w3(const float* __restrict__ pbuf,
                                              const float* __restrict__ gg,
                                              const float* __restrict__ bb,
                                              const float* __restrict__ W,  // g2_w1 [112][32]
                                              unsigned short* __restrict__ w3h,
                                              unsigned short* __restrict__ w3l,
                                              float* __restrict__ c0, int M) {
    __shared__ double red[256];
    __shared__ float sv[2];
    int j = blockIdx.x;
    int t = threadIdx.x;
    double sum = 0.0, sq = 0.0;
    for (int i = t; i < GEMM_MB; i += 256) {
        sum += (double)pbuf[(size_t)i * 2 * F_IN + j];
        sq  += (double)pbuf[(size_t)i * 2 * F_IN + F_IN + j];
    }
    red[t] = sum;
    __syncthreads();
    for (int o = 128; o > 0; o >>= 1) { if (t < o) red[t] += red[t + o]; __syncthreads(); }
    double total_sum = red[0];
    __syncthreads();
    red[t] = sq;
    __syncthreads();
    for (int o = 128; o > 0; o >>= 1) { if (t < o) red[t] += red[t + o]; __syncthreads(); }
    if (t == 0) {
        double mean = total_sum / M;
        double var = red[0] / M - mean * mean;
        double sc = (double)gg[j] / sqrt(var + BN_EPS);
        sv[0] = (float)sc;
        sv[1] = (float)((double)bb[j] - mean * sc);
    }
    __syncthreads();
    if (t < DIM) {
        float w = W[(size_t)j * DIM + t];
        float v = sv[0] * w;
        unsigned short h = f2h_u(v);
        w3h[t * 128 + j] = h;
        w3l[t * 128 + j] = f2h_u(v - h2f_u(h));
        atomicAdd(&c0[t], sv[1] * w);
    }
}

// ---------- fp16 MFMA GEMM: C/Ch = act(A_f16 @ W + bias), W fp16 hi+lo
template <int NT, int KC, int AS, bool RELU, int CHS, bool STATS>
__global__ __launch_bounds__(256) void gemm_mfma_h(const unsigned short* __restrict__ A,
                                                   const unsigned short* __restrict__ Whi,
                                                   const unsigned short* __restrict__ Wlo,
                                                   const float* __restrict__ bias,
                                                   float* __restrict__ C,
                                                   __half* __restrict__ Ch,
                                                   float* __restrict__ pbuf, int M) {
    constexpr int N = NT * 16;
    constexpr int Kpad = KC * 32;
    __shared__ __align__(16) unsigned short Ah[64 * 32];
    __shared__ __align__(16) unsigned short Wh[N * 32];
    __shared__ __align__(16) unsigned short Wl[N * 32];
    int t = threadIdx.x;
    int lane = t & 63, wid = t >> 6;
    int r0 = blockIdx.x * 64;
    int m = lane & 15, quad = lane >> 4;

    float4v acc[NT];
#pragma unroll
    for (int nt = 0; nt < NT; nt++) acc[nt] = (float4v){0.f, 0.f, 0.f, 0.f};

    for (int c = 0; c < KC; c++) {
        int kc = c * 32;
        {
            int row = t >> 2, seg = t & 3;
            int grow = r0 + row;
            uint4 v = make_uint4(0, 0, 0, 0);
            if (grow < M) v = *(const uint4*)(A + (size_t)grow * AS + kc + seg * 8);
            *(uint4*)&Ah[row * 32 + seg * 8] = v;
        }
        for (int idx = t; idx < N * 8; idx += 256) {
            int n = idx >> 3, w = idx & 7;
            int gsrc = n * (Kpad / 4) + (kc >> 2) + w;
            ((uint2*)Wh)[idx] = ((const uint2*)Whi)[gsrc];
            ((uint2*)Wl)[idx] = ((const uint2*)Wlo)[gsrc];
        }
        __syncthreads();
        half8 a = *(const half8*)&Ah[(wid * 16 + m) * 32 + quad * 8];
#pragma unroll
        for (int nt = 0; nt < NT; nt++) {
            half8 b_h = *(const half8*)&Wh[(nt * 16 + m) * 32 + quad * 8];
            half8 b_l = *(const half8*)&Wl[(nt * 16 + m) * 32 + quad * 8];
            acc[nt] = __builtin_amdgcn_mfma_f32_16x16x32_f16(a, b_h, acc[nt], 0, 0, 0);
            acc[nt] = __builtin_amdgcn_mfma_f32_16x16x32_f16(a, b_l, acc[nt], 0, 0, 0);
        }
        __syncthreads();
    }
    float st_s[NT], st_q[NT];
#pragma unroll
    for (int nt = 0; nt < NT; nt++) {
        int col = nt * 16 + m;
        float b = bias ? bias[col] : 0.f;
        float s_loc = 0.f, q_loc = 0.f;
#pragma unroll
        for (int r = 0; r < 4; r++) {
            int row = r0 + wid * 16 + quad * 4 + r;
            float v = acc[nt][r] + b;
            if (RELU) v = fmaxf(v, 0.f);
            if (row < M) {
                if (C) C[(size_t)row * N + col] = v;
                if (Ch) Ch[(size_t)row * CHS + col] = __float2half(v);
                if (STATS) { s_loc += v; q_loc += v * v; }
            }
        }
        st_s[nt] = s_loc;
        st_q[nt] = q_loc;
    }
    if constexpr (STATS) {
        __shared__ float sls[4][2 * N];
#pragma unroll
        for (int nt = 0; nt < NT; nt++) {
            float s = st_s[nt], q = st_q[nt];
            s += __shfl_xor(s, 16); s += __shfl_xor(s, 32);
            q += __shfl_xor(q, 16); q += __shfl_xor(q, 32);
            if (quad == 0) {
                sls[wid][nt * 16 + m] = s;
                sls[wid][N + nt * 16 + m] = q;
            }
        }
        __syncthreads();
        for (int j = t; j < 2 * N; j += 256) {
            pbuf[(size_t)blockIdx.x * 2 * N + j] = sls[0][j] + sls[1][j] + sls[2][j] + sls[3][j];
        }
    }
}

// ------- FUSED GIN layer 2 tail: per-block 32-wide gather (agg32, with
// c0/b1/relu) into LDS, then H2 = relu(S@W4+b2) fp32 out + BN2 stats.
__global__ __launch_bounds__(256) void gin2_fused(const __half* __restrict__ Y,
        const int* __restrict__ deg_arr,
        const unsigned short* __restrict__ perm_pad,
        const float* __restrict__ c0, const float* __restrict__ cb1,
        const unsigned short* __restrict__ W4h, const unsigned short* __restrict__ W4l,
        const float* __restrict__ bias,
        float* __restrict__ C, float* __restrict__ pbuf, int M) {
    constexpr int NT = 2, N = 32;
    __shared__ __align__(16) unsigned short As[64 * 32];
    __shared__ __align__(16) unsigned short Wh[N * 32];
    __shared__ __align__(16) unsigned short Wl[N * 32];
    __shared__ float sls[4][2 * N];
    int t = threadIdx.x;
    int lane = t & 63, wid = t >> 6;
    int r0 = blockIdx.x * 64;
    int m = lane & 15, quad = lane >> 4;
    int f = m, g = quad;

    // stage W4 (single K-chunk) under the gather
    for (int idx = t; idx < N * 8; idx += 256) {
        int n = idx >> 3, w = idx & 7;
        int gsrc = n * 8 + w;
        ((uint2*)Wh)[idx] = ((const uint2*)W4h)[gsrc];
        ((uint2*)Wl)[idx] = ((const uint2*)W4l)[gsrc];
    }

    for (int i = 0; i < 16; i++) {
        int row = wid * 16 + i;
        int grow = r0 + row;
        float ax = 0.f, ay = 0.f;
        int deg = 0;
        if (grow < M) {
            deg = deg_arr[grow];
            const unsigned short* pl = perm_pad + (size_t)grow * CAP;
            int e = g;
            for (; e + 4 < deg; e += 8) {
                int s0 = pl[e], s1 = pl[e + 4];
                float2 v0 = __half22float2(*(const __half2*)(Y + (size_t)s0 * DIM + 2 * f));
                float2 v1 = __half22float2(*(const __half2*)(Y + (size_t)s1 * DIM + 2 * f));
                ax += v0.x + v1.x;
                ay += v0.y + v1.y;
            }
            if (e < deg) {
                int s0 = pl[e];
                float2 v0 = __half22float2(*(const __half2*)(Y + (size_t)s0 * DIM + 2 * f));
                ax += v0.x;
                ay += v0.y;
            }
        }
        ax += __shfl_xor(ax, 16); ax += __shfl_xor(ax, 32);
        ay += __shfl_xor(ay, 16); ay += __shfl_xor(ay, 32);
        if (g == 0) {
            __half2 hv = __floats2half2_rn(0.f, 0.f);
            if (grow < M) {
                float2 self = __half22float2(*(const __half2*)(Y + (size_t)grow * DIM + 2 * f));
                float deg1 = (float)(deg + 1);
                float zx = fmaxf(self.x + ax + deg1 * c0[2 * f] + cb1[2 * f], 0.f);
                float zy = fmaxf(self.y + ay + deg1 * c0[2 * f + 1] + cb1[2 * f + 1], 0.f);
                hv = __floats2half2_rn(zx, zy);
            }
            ((__half2*)&As[row * 32])[f] = hv;
        }
    }
    __syncthreads();

    float4v acc[NT];
#pragma unroll
    for (int nt = 0; nt < NT; nt++) acc[nt] = (float4v){0.f, 0.f, 0.f, 0.f};
    half8 a = *(const half8*)&As[(wid * 16 + m) * 32 + quad * 8];
#pragma unroll
    for (int nt = 0; nt < NT; nt++) {
        half8 b_h = *(const half8*)&Wh[(nt * 16 + m) * 32 + quad * 8];
        half8 b_l = *(const half8*)&Wl[(nt * 16 + m) * 32 + quad * 8];
        acc[nt] = __builtin_amdgcn_mfma_f32_16x16x32_f16(a, b_h, acc[nt], 0, 0, 0);
        acc[nt] = __builtin_amdgcn_mfma_f32_16x16x32_f16(a, b_l, acc[nt], 0, 0, 0);
    }

    float st_s[NT], st_q[NT];
#pragma unroll
    for (int nt = 0; nt < NT; nt++) {
        int col = nt * 16 + m;
        float b = bias[col];
        float s_loc = 0.f, q_loc = 0.f;
#pragma unroll
        for (int r = 0; r < 4; r++) {
            int row = r0 + wid * 16 + quad * 4 + r;
            float v = fmaxf(acc[nt][r] + b, 0.f);
            if (row < M) {
                C[(size_t)row * N + col] = v;
                s_loc += v;
                q_loc += v * v;
            }
        }
        st_s[nt] = s_loc;
        st_q[nt] = q_loc;
    }
#pragma unroll
    for (int nt = 0; nt < NT; nt++) {
        float s = st_s[nt], q = st_q[nt];
        s += __shfl_xor(s, 16); s += __shfl_xor(s, 32);
        q += __shfl_xor(q, 16); q += __shfl_xor(q, 32);
        if (quad == 0) {
            sls[wid][nt * 16 + m] = s;
            sls[wid][N + nt * 16 + m] = q;
        }
    }
    __syncthreads();
    for (int j = t; j < 2 * N; j += 256) {
        pbuf[(size_t)blockIdx.x * 2 * N + j] = sls[0][j] + sls[1][j] + sls[2][j] + sls[3][j];
    }
}

// --------- parallel BN finalize: one block per feature, 256-thread reduce
template <int F, int BLOCKS>
__global__ __launch_bounds__(256) void bn_finalize_par(const float* __restrict__ pbuf,
                                                       const float* __restrict__ g,
                                                       const float* __restrict__ b,
                                                       float* __restrict__ s,
                                                       float* __restrict__ tt, int M) {
    __shared__ double red[256];
    int j = blockIdx.x;
    int t = threadIdx.x;
    double sum = 0.0, sq = 0.0;
    for (int i = t; i < BLOCKS; i += 256) {
        sum += (double)pbuf[(size_t)i * 2 * F + j];
        sq  += (double)pbuf[(size_t)i * 2 * F + F + j];
    }
    red[t] = sum;
    __syncthreads();
    for (int o = 128; o > 0; o >>= 1) { if (t < o) red[t] += red[t + o]; __syncthreads(); }
    double total_sum = red[0];
    __syncthreads();
    red[t] = sq;
    __syncthreads();
    for (int o = 128; o > 0; o >>= 1) { if (t < o) red[t] += red[t + o]; __syncthreads(); }
    if (t == 0) {
        double mean = total_sum / M;
        double var = red[0] / M - mean * mean;
        double sc = (double)g[j] / sqrt(var + BN_EPS);
        s[j] = (float)sc;
        tt[j] = (float)((double)b[j] - mean * sc);
    }
}

// -------------------------------------------- pool (BN2 folded) + head
__global__ __launch_bounds__(256) void pool_head(const float* __restrict__ H2, const int* __restrict__ goff,
                                                 const float* __restrict__ s2, const float* __restrict__ t2,
                                                 const float* __restrict__ fcxd_w, const float* __restrict__ fcxd_b,
                                                 const float* __restrict__ fc1_w, const float* __restrict__ fc1_b,
                                                 const float* __restrict__ fc2_w, const float* __restrict__ fc2_b,
                                                 const float* __restrict__ fc3_w, const float* __restrict__ fc3_b,
                                                 const float* __restrict__ fc4_w, const float* __restrict__ fc4_b,
                                                 const float* __restrict__ fc5_w, const float* __restrict__ fc5_b,
                                                 float* __restrict__ out) {
    __shared__ float red[256];
    __shared__ float p[64];
    __shared__ float z[64];
    int g = blockIdx.x, t = threadIdx.x;
    int r0 = goff[g], r1 = goff[g + 1];
    int cnt = r1 - r0;
    int j = t & 31, rr = t >> 5;
    float a = 0.f;
    for (int r = r0 + rr; r < r1; r += 8) a += H2[(size_t)r * DIM + j];
    red[t] = a;
    __syncthreads();
    if (t < 32) {
        float ssum = 0.f;
        for (int q = 0; q < 8; q++) ssum += red[q * 32 + j];
        p[j] = s2[j] * ssum + (float)cnt * t2[j];
    }
    __syncthreads();
    if (t < 64) {
        float acc = fcxd_b[t];
        for (int i = 0; i < 32; i++) acc += p[i] * fcxd_w[i * 64 + t];
        z[t] = fmaxf(acc, 0.f);
    }
    __syncthreads();
    if (t < 32) {
        float acc = fc1_b[t];
        for (int i = 0; i < 64; i++) acc += z[i] * fc1_w[i * 32 + t];
        p[t] = acc;
    }
    __syncthreads();
    if (t < 16) {
        float acc = fc2_b[t];
        for (int i = 0; i < 32; i++) acc += p[i] * fc2_w[i * 16 + t];
        z[t] = acc;
    }
    __syncthreads();
    if (t < 8) {
        float acc = fc3_b[t];
        for (int i = 0; i < 16; i++) acc += z[i] * fc3_w[i * 8 + t];
        p[t] = acc;
    }
    __syncthreads();
    if (t < 2) {
        float acc = fc4_b[t];
        for (int i = 0; i < 8; i++) acc += p[i] * fc4_w[i * 2 + t];
        z[t] = acc;
    }
    __syncthreads();
    if (t == 0) {
        out[g] = z[0] * fc5_w[0] + z[1] * fc5_w[1] + fc5_b[0];
    }
}

// ---------------------------------------------------------------- launch
extern "C" void kernel_launch(void* const* d_in, const int* in_sizes, int n_in,
                              void* d_out, int out_size, void* d_ws, size_t ws_size,
                              hipStream_t stream) {
    const float* x     = (const float*)d_in[0];
    const int*   src   = (const int*)d_in[1];
    const int*   dst   = (const int*)d_in[2];
    const int*   batch = (const int*)d_in[3];
    const float* g1_w1 = (const float*)d_in[4];
    const float* g1_b1 = (const float*)d_in[5];
    const float* g1_w2 = (const float*)d_in[6];
    const float* g1_b2 = (const float*)d_in[7];
    const float* bn1_g = (const float*)d_in[8];
    const float* bn1_b = (const float*)d_in[9];
    const float* g2_w1 = (const float*)d_in[10];
    const float* g2_b1 = (const float*)d_in[11];
    const float* g2_w2 = (const float*)d_in[12];
    const float* g2_b2 = (const float*)d_in[13];
    const float* bn2_g = (const float*)d_in[14];
    const float* bn2_b = (const float*)d_in[15];
    const float* fcxd_w = (const float*)d_in[16];
    const float* fcxd_b = (const float*)d_in[17];
    const float* fc1_w = (const float*)d_in[18];
    const float* fc1_b = (const float*)d_in[19];
    const float* fc2_w = (const float*)d_in[20];
    const float* fc2_b = (const float*)d_in[21];
    const float* fc3_w = (const float*)d_in[22];
    const float* fc3_b = (const float*)d_in[23];
    const float* fc4_w = (const float*)d_in[24];
    const float* fc4_b = (const float*)d_in[25];
    const float* fc5_w = (const float*)d_in[26];
    const float* fc5_b = (const float*)d_in[27];
    float* out = (float*)d_out;
    char* ws = (char*)d_ws;

    size_t off = 0;
    auto take = [&](size_t bytes) { size_t o = off; off += (bytes + 255) & ~(size_t)255; return o; };
    // ---- zeroed region: gcur + c0 + w3 hi/lo (pad rows k>=112 must be 0)
    int* gcur      = (int*)(ws + take((size_t)CB * 4));
    float* c0      = (float*)(ws + take(DIM * 4));
    unsigned short* w3h = (unsigned short*)(ws + take((size_t)DIM * 128 * 2));
    unsigned short* w3l = (unsigned short*)(ws + take((size_t)DIM * 128 * 2));
    size_t zero_bytes = off;
    // ---- rest
    int* bucket    = (int*)(ws + take((size_t)CB * CBCAP * 4));
    unsigned short* perm_pad = (unsigned short*)(ws + take((size_t)N_NODES * CAP * 2));
    int* deg       = (int*)(ws + take((size_t)N_NODES * 4));
    int* goff      = (int*)(ws + take((size_t)(N_GRAPHS + 4) * 4));
    float* s2      = (float*)(ws + take(DIM * 4));
    float* t2      = (float*)(ws + take(DIM * 4));
    float* pb1     = (float*)(ws + take((size_t)GEMM_MB * 2 * F_IN * 4));
    float* pb2     = (float*)(ws + take((size_t)GEMM_MB * 2 * DIM * 4));
    unsigned short* w1h = (unsigned short*)(ws + take((size_t)F_IN * 128 * 2));
    unsigned short* w1l = (unsigned short*)(ws + take((size_t)F_IN * 128 * 2));
    unsigned short* w2h = (unsigned short*)(ws + take((size_t)F_IN * 128 * 2));
    unsigned short* w2l = (unsigned short*)(ws + take((size_t)F_IN * 128 * 2));
    unsigned short* w4h = (unsigned short*)(ws + take((size_t)DIM * 32 * 2));
    unsigned short* w4l = (unsigned short*)(ws + take((size_t)DIM * 32 * 2));
    __half* x_half = (__half*)(ws + take((size_t)N_NODES * HROW * 2));
    __half* h1h    = (__half*)(ws + take((size_t)N_NODES * HROW * 2));
    __half* y_half = (__half*)(ws + take((size_t)N_NODES * DIM * 2));
    float* bufS2   = (float*)(ws + take((size_t)N_NODES * DIM * 4));
    (void)ws_size; (void)in_sizes; (void)n_in; (void)out_size;

    hipMemsetAsync(ws, 0, zero_bytes, stream);

    // graph build: edge partition overlapped with prep in one kernel
    build_kernel<<<MB_GB, 1024, 0, stream>>>(src, dst, gcur, bucket,
                                             x, x_half,
                                             g1_w1, w1h, w1l, g1_w2, w2h, w2l, g2_w2, w4h, w4l,
                                             batch, goff);
    bin_build<<<CB, 1024, 0, stream>>>(gcur, bucket, perm_pad, deg);

    // GIN layer 1: fused gather + MLP (+BN1 stats), then BN1 finalize + W3 fold
    gin1_fused<<<GEMM_MB, 256, 0, stream>>>(x, x_half, deg, perm_pad,
                                            w1h, w1l, g1_b1, w2h, w2l, g1_b2,
                                            h1h, pb1, N_NODES);
    bn1_w3<<<F_IN, 256, 0, stream>>>(pb1, bn1_g, bn1_b, g2_w1, w3h, w3l, c0, N_NODES);

    // GIN layer 2: linear-first (BN1 folded), then fused gather + MLP2 (+BN2 stats)
    gemm_mfma_h<2, 4, HROW, false, DIM, false><<<GEMM_MB, 256, 0, stream>>>(
        (const unsigned short*)h1h, w3h, w3l, nullptr, nullptr, y_half, nullptr, N_NODES);
    gin2_fused<<<GEMM_MB, 256, 0, stream>>>(y_half, deg, perm_pad, c0, g2_b1,
                                            w4h, w4l, g2_b2, bufS2, pb2, N_NODES);
    bn_finalize_par<DIM, GEMM_MB><<<DIM, 256, 0, stream>>>(pb2, bn2_g, bn2_b, s2, t2, N_NODES);

    // pool (BN2 folded) + dense head
    pool_head<<<N_GRAPHS, 256, 0, stream>>>(bufS2, goff, s2, t2,
                                            fcxd_w, fcxd_b, fc1_w, fc1_b, fc2_w, fc2_b,
                                            fc3_w, fc3_b, fc4_w, fc4_b, fc5_w, fc5_b, out);
}

// Round 4
// 241.087 us; speedup vs baseline: 1.3360x; 1.3360x over previous
//
#include <hip/hip_runtime.h>
#include <hip/hip_fp16.h>

#define N_NODES 50000
#define N_GRAPHS 256
#define N_EDGES 800000
#define F_IN 112
#define DIM 32
#define BN_EPS 1e-5
#define HROW 128   // fp16 row stride (256 B)
#define CAP 64     // edge slots per node
#define CB 391     // coarse buckets of 128 nodes
#define CBCAP 2560
#define CHUNK 8192
#define NPART 98
#define GEMM_MB 782 // ceil(50000/64)
#define WS 40      // W/A LDS row stride in halves: 80 B = 5 x 16 B (aligned), bank stride 20 -> 2-way (free)

typedef __attribute__((ext_vector_type(8))) _Float16 half8;
typedef __attribute__((ext_vector_type(4))) float float4v;

__device__ inline unsigned short f2h_u(float f) {
    union { __half h; unsigned short u; } v; v.h = __float2half(f); return v.u;
}
__device__ inline float h2f_u(unsigned short u) {
    union { unsigned short u; __half h; } v; v.u = u; return __half2float(v.h);
}

__device__ inline void acc8(const uint4& u, float* ax) {
    const __half2* h = (const __half2*)&u;
#pragma unroll
    for (int p = 0; p < 4; p++) {
        float2 f = __half22float2(h[p]);
        ax[2 * p] += f.x;
        ax[2 * p + 1] += f.y;
    }
}

// W[KxN] fp32 -> hi/lo fp16 [N][Kpad] (transposed, zero-padded)
__device__ inline void w_split_body(const float* __restrict__ W, int K, int N, int Kpad,
                                    unsigned short* __restrict__ hi_t,
                                    unsigned short* __restrict__ lo_t, int idx) {
    if (idx >= N * Kpad) return;
    int n = idx / Kpad, k = idx - n * Kpad;
    float v = (k < K) ? W[(size_t)k * N + n] : 0.f;
    unsigned short h = f2h_u(v);
    hi_t[idx] = h;
    lo_t[idx] = f2h_u(v - h2f_u(h));
}

// ---- MERGED build kernel: edge partition (blocks 0..NPART-1) + prep work
// Xh gets one extra zeroed sentinel row (index N_NODES) for branch-free gather.
#define MB_P  NPART
#define MB_XH (MB_P + 3126)   // 50001*64 half2 / 1024 (incl. sentinel row)
#define MB_W1 (MB_XH + 14)
#define MB_W2 (MB_W1 + 14)
#define MB_W4 (MB_W2 + 1)
#define MB_GB (MB_W4 + 49)
__global__ __launch_bounds__(1024) void build_kernel(
        const int* __restrict__ src, const int* __restrict__ dst,
        int* __restrict__ gcur,     // [CB], zeroed
        int* __restrict__ bucket,   // [CB][CBCAP]
        const float* __restrict__ X, __half* __restrict__ Xh,
        const float* __restrict__ g1_w1, unsigned short* w1h, unsigned short* w1l,
        const float* __restrict__ g1_w2, unsigned short* w2h, unsigned short* w2l,
        const float* __restrict__ g2_w2, unsigned short* w4h, unsigned short* w4l,
        const int* __restrict__ batch, int* __restrict__ goff) {
    int b = blockIdx.x;
    int t = threadIdx.x;
    if (b < MB_P) {
        __shared__ int hist[512];
        __shared__ int lofs[512];
        __shared__ int lcur[512];
        __shared__ int gbase[512];
        __shared__ int staging[CHUNK];
        int base = b * CHUNK;
        int total = min(CHUNK, N_EDGES - base);
        for (int i = t; i < 512; i += 1024) hist[i] = 0;
        __syncthreads();
        int d[8], s[8];
#pragma unroll
        for (int j = 0; j < 8; j++) {
            int i = base + j * 1024 + t;
            if (i < N_EDGES) {
                d[j] = __builtin_nontemporal_load(dst + i);
                s[j] = __builtin_nontemporal_load(src + i);
            } else {
                d[j] = -1;
            }
        }
#pragma unroll
        for (int j = 0; j < 8; j++) {
            if (d[j] >= 0) atomicAdd(&hist[d[j] >> 7], 1);
        }
        __syncthreads();
        if (t < 512) lofs[t] = hist[t];
        __syncthreads();
        for (int o = 1; o < 512; o <<= 1) {
            int add = (t < 512 && t >= o) ? lofs[t - o] : 0;
            __syncthreads();
            if (t < 512) lofs[t] += add;
            __syncthreads();
        }
        if (t < CB) {
            gbase[t] = (hist[t] > 0) ? atomicAdd(&gcur[t], hist[t]) : 0;
        }
        if (t < 512) lcur[t] = lofs[t] - hist[t];
        __syncthreads();
#pragma unroll
        for (int j = 0; j < 8; j++) {
            if (d[j] >= 0) {
                int bb = d[j] >> 7;
                int p = atomicAdd(&lcur[bb], 1);
                staging[p] = (d[j] << 16) | s[j];
            }
        }
        __syncthreads();
        for (int p = t; p < total; p += 1024) {
            int e = staging[p];
            int bb = ((unsigned)e >> 16) >> 7;
            int ls = lofs[bb] - hist[bb];
            int di = gbase[bb] + (p - ls);
            if (di < CBCAP) bucket[(size_t)bb * CBCAP + di] = e;
        }
    } else if (b < MB_XH) {
        int idx = (b - MB_P) * 1024 + t;
        if (idx >= (N_NODES + 1) * (HROW / 2)) return;
        int row = idx >> 6, c2 = idx & 63;
        int col = c2 * 2;
        float2 v = make_float2(0.f, 0.f);
        if (row < N_NODES && col < F_IN) v = *(const float2*)(X + (size_t)row * F_IN + col);
        ((__half2*)Xh)[idx] = __floats2half2_rn(v.x, v.y);
    } else if (b < MB_W1) {
        w_split_body(g1_w1, F_IN, F_IN, 128, w1h, w1l, (b - MB_XH) * 1024 + t);
    } else if (b < MB_W2) {
        w_split_body(g1_w2, F_IN, F_IN, 128, w2h, w2l, (b - MB_W1) * 1024 + t);
    } else if (b < MB_W4) {
        w_split_body(g2_w2, DIM, DIM, 32, w4h, w4l, (b - MB_W2) * 1024 + t);
    } else {
        int i = (b - MB_W4) * 1024 + t;
        if (i >= N_NODES) return;
        int cur = batch[i];
        int prev = (i == 0) ? -1 : batch[i - 1];
        for (int g = prev + 1; g <= cur; g++) goff[g] = i;
        if (i == N_NODES - 1) {
            for (int g = cur + 1; g <= N_GRAPHS; g++) goff[g] = N_NODES;
        }
    }
}

// ---- bin_build: sentinel-padded (node N_NODES) perm lists, u16, coalesced
__global__ __launch_bounds__(1024) void bin_build(const int* __restrict__ gcur,
                                                  const int* __restrict__ bucket,
                                                  unsigned short* __restrict__ perm_pad,
                                                  int* __restrict__ deg) {
    __shared__ __align__(16) unsigned short bins[128][CAP];   // 16 KB
    __shared__ int lcur[128];
    int b = blockIdx.x, t = threadIdx.x;
    for (int i = t; i < 128 * CAP; i += 1024) ((unsigned short*)bins)[i] = (unsigned short)N_NODES;
    if (t < 128) lcur[t] = 0;
    __syncthreads();
    int count = min(gcur[b], CBCAP);
    for (int i = t; i < count; i += 1024) {
        int e = bucket[(size_t)b * CBCAP + i];
        int l = ((unsigned)e >> 16) & 127;
        int s = e & 0xFFFF;
        int c = atomicAdd(&lcur[l], 1);
        if (c < CAP) bins[l][c] = (unsigned short)s;
    }
    __syncthreads();
    if (t < 128) {
        int node = b * 128 + t;
        if (node < N_NODES) deg[node] = min(lcur[t], CAP);
    }
    for (int i = t; i < 128 * (CAP / 8); i += 1024) {
        int l = i >> 3, q = i & 7;
        int node = b * 128 + l;
        if (node < N_NODES) {
            ((int4*)&perm_pad[(size_t)node * CAP])[q] = ((const int4*)bins[l])[q];
        }
    }
}

// ------- FUSED GIN layer 1 (1024 thr, 2 blocks/CU = 32 waves/CU):
// 16B-lane gather -> LDS A-tile -> relu(relu(A@W1+b1)@W2+b2) + BN1 stats.
// Each of the 16 waves gathers 4 rows (16*4 = 64 = tile rows).
__global__ __launch_bounds__(1024, 8) void gin1_fused(const float* __restrict__ X,
        const __half* __restrict__ Xh,
        const int* __restrict__ deg_arr,
        const unsigned short* __restrict__ perm_pad,
        const unsigned short* __restrict__ W1h, const unsigned short* __restrict__ W1l,
        const float* __restrict__ b1,
        const unsigned short* __restrict__ W2h, const unsigned short* __restrict__ W2l,
        const float* __restrict__ b2,
        __half* __restrict__ Ch, float* __restrict__ pbuf, int M) {
    constexpr int N = 112, Kpad = 128, TS = 136, AS = 136;
    __shared__ __align__(16) unsigned short Afull[64 * AS];  // 17 KB (aliased as sls later)
    __shared__ __align__(16) unsigned short T1[64 * TS];     // 17 KB
    __shared__ __align__(16) unsigned short Wh[N * WS];      // 8.75 KB
    __shared__ __align__(16) unsigned short Wl[N * WS];      // 8.75 KB
    float* sls = (float*)Afull;
    int t = threadIdx.x;
    int lane = t & 63, wid = t >> 6;          // 16 waves
    int r0 = blockIdx.x * 64;
    int m = lane & 15, quad = lane >> 4;
    int rg = wid & 3, ng = wid >> 2;          // row-group, n-group
    int nt0 = ng, nt1 = ng + 4;
    bool has1 = (nt1 < 7);

    // pre-stage W1 chunk 0 (completes under the gather)
    for (int idx = t; idx < N * 8; idx += 1024) {
        int n = idx >> 3, w = idx & 7;
        int gsrc = n * (Kpad / 4) + w;
        ((uint2*)&Wh[n * WS])[w] = ((const uint2*)W1h)[gsrc];
        ((uint2*)&Wl[n * WS])[w] = ((const uint2*)W1l)[gsrc];
    }

    // ---- gather: wave wid builds rows wid*4 .. wid*4+3 (FIX: was wid*8+[0,8))
    // lane = (eg 0..3 edge stripes) x (fl 0..15 16B feature segments)
    int fl = lane & 15, eg = lane >> 4;
#pragma unroll 1
    for (int i = 0; i < 4; i++) {
        int row = wid * 4 + i;
        int grow = r0 + row;
        float ax[8] = {0.f, 0.f, 0.f, 0.f, 0.f, 0.f, 0.f, 0.f};
        if (grow < M) {
            int deg = deg_arr[grow];
            const unsigned short* pl = perm_pad + (size_t)grow * CAP;
            int nb = (deg + 3) >> 2;   // batches of 4 edges
#pragma unroll 1
            for (int b = 0; b < nb; b += 4) {   // sentinel-padded: slots always valid
                int s0 = pl[(b + 0) * 4 + eg];
                int s1 = pl[(b + 1) * 4 + eg];
                int s2 = pl[(b + 2) * 4 + eg];
                int s3 = pl[(b + 3) * 4 + eg];
                uint4 u0 = *(const uint4*)(Xh + (size_t)s0 * HROW + fl * 8);
                uint4 u1 = *(const uint4*)(Xh + (size_t)s1 * HROW + fl * 8);
                uint4 u2 = *(const uint4*)(Xh + (size_t)s2 * HROW + fl * 8);
                uint4 u3 = *(const uint4*)(Xh + (size_t)s3 * HROW + fl * 8);
                acc8(u0, ax); acc8(u1, ax); acc8(u2, ax); acc8(u3, ax);
            }
        }
#pragma unroll
        for (int p = 0; p < 8; p++) {
            ax[p] += __shfl_xor(ax[p], 16);
            ax[p] += __shfl_xor(ax[p], 32);
        }
        if (eg == 0) {
            if (grow < M && fl < 14) {   // 14*8 = 112 = F_IN
                float4 sa = *(const float4*)(X + (size_t)grow * F_IN + fl * 8);
                float4 sb = *(const float4*)(X + (size_t)grow * F_IN + fl * 8 + 4);
                ax[0] += sa.x; ax[1] += sa.y; ax[2] += sa.z; ax[3] += sa.w;
                ax[4] += sb.x; ax[5] += sb.y; ax[6] += sb.z; ax[7] += sb.w;
            }
            uint4 o;
            __half2* oh = (__half2*)&o;
#pragma unroll
            for (int p = 0; p < 4; p++) oh[p] = __floats2half2_rn(ax[2 * p], ax[2 * p + 1]);
            *(uint4*)&Afull[row * AS + fl * 8] = o;
        }
    }
    // T1 pad columns zero
    {
        int i = t;  // 64*16 == 1024
        T1[(i >> 4) * TS + 112 + (i & 15)] = 0;
    }

    float4v acc0 = {0.f, 0.f, 0.f, 0.f}, acc1 = {0.f, 0.f, 0.f, 0.f};

    // ---- phase 1: T = relu(A@W1+b1)
    for (int c = 0; c < 4; c++) {
        int kc = c * 32;
        if (c > 0) {
            for (int idx = t; idx < N * 8; idx += 1024) {
                int n = idx >> 3, w = idx & 7;
                int gsrc = n * (Kpad / 4) + (kc >> 2) + w;
                ((uint2*)&Wh[n * WS])[w] = ((const uint2*)W1h)[gsrc];
                ((uint2*)&Wl[n * WS])[w] = ((const uint2*)W1l)[gsrc];
            }
        }
        __syncthreads();
        half8 a = *(const half8*)&Afull[(rg * 16 + m) * AS + kc + quad * 8];
        {
            half8 bh = *(const half8*)&Wh[(nt0 * 16 + m) * WS + quad * 8];
            half8 bl = *(const half8*)&Wl[(nt0 * 16 + m) * WS + quad * 8];
            acc0 = __builtin_amdgcn_mfma_f32_16x16x32_f16(a, bh, acc0, 0, 0, 0);
            acc0 = __builtin_amdgcn_mfma_f32_16x16x32_f16(a, bl, acc0, 0, 0, 0);
        }
        if (has1) {
            half8 bh = *(const half8*)&Wh[(nt1 * 16 + m) * WS + quad * 8];
            half8 bl = *(const half8*)&Wl[(nt1 * 16 + m) * WS + quad * 8];
            acc1 = __builtin_amdgcn_mfma_f32_16x16x32_f16(a, bh, acc1, 0, 0, 0);
            acc1 = __builtin_amdgcn_mfma_f32_16x16x32_f16(a, bl, acc1, 0, 0, 0);
        }
        __syncthreads();
    }

    {
        int col = nt0 * 16 + m;
        float bb = b1[col];
#pragma unroll
        for (int r = 0; r < 4; r++)
            T1[(rg * 16 + quad * 4 + r) * TS + col] = f2h_u(fmaxf(acc0[r] + bb, 0.f));
        acc0 = (float4v){0.f, 0.f, 0.f, 0.f};
    }
    if (has1) {
        int col = nt1 * 16 + m;
        float bb = b1[col];
#pragma unroll
        for (int r = 0; r < 4; r++)
            T1[(rg * 16 + quad * 4 + r) * TS + col] = f2h_u(fmaxf(acc1[r] + bb, 0.f));
        acc1 = (float4v){0.f, 0.f, 0.f, 0.f};
    }
    __syncthreads();

    // ---- phase 2: H1 = relu(T@W2+b2)
    for (int c = 0; c < 4; c++) {
        int kc = c * 32;
        for (int idx = t; idx < N * 8; idx += 1024) {
            int n = idx >> 3, w = idx & 7;
            int gsrc = n * (Kpad / 4) + (kc >> 2) + w;
            ((uint2*)&Wh[n * WS])[w] = ((const uint2*)W2h)[gsrc];
            ((uint2*)&Wl[n * WS])[w] = ((const uint2*)W2l)[gsrc];
        }
        __syncthreads();
        half8 a = *(const half8*)&T1[(rg * 16 + m) * TS + kc + quad * 8];
        {
            half8 bh = *(const half8*)&Wh[(nt0 * 16 + m) * WS + quad * 8];
            half8 bl = *(const half8*)&Wl[(nt0 * 16 + m) * WS + quad * 8];
            acc0 = __builtin_amdgcn_mfma_f32_16x16x32_f16(a, bh, acc0, 0, 0, 0);
            acc0 = __builtin_amdgcn_mfma_f32_16x16x32_f16(a, bl, acc0, 0, 0, 0);
        }
        if (has1) {
            half8 bh = *(const half8*)&Wh[(nt1 * 16 + m) * WS + quad * 8];
            half8 bl = *(const half8*)&Wl[(nt1 * 16 + m) * WS + quad * 8];
            acc1 = __builtin_amdgcn_mfma_f32_16x16x32_f16(a, bh, acc1, 0, 0, 0);
            acc1 = __builtin_amdgcn_mfma_f32_16x16x32_f16(a, bl, acc1, 0, 0, 0);
        }
        __syncthreads();
    }

    float st_s0 = 0.f, st_q0 = 0.f, st_s1 = 0.f, st_q1 = 0.f;
    {
        int col = nt0 * 16 + m;
        float bb = b2[col];
#pragma unroll
        for (int r = 0; r < 4; r++) {
            int row = r0 + rg * 16 + quad * 4 + r;
            float v = fmaxf(acc0[r] + bb, 0.f);
            if (row < M) {
                Ch[(size_t)row * HROW + col] = __float2half(v);
                st_s0 += v;
                st_q0 += v * v;
            }
        }
    }
    if (has1) {
        int col = nt1 * 16 + m;
        float bb = b2[col];
#pragma unroll
        for (int r = 0; r < 4; r++) {
            int row = r0 + rg * 16 + quad * 4 + r;
            float v = fmaxf(acc1[r] + bb, 0.f);
            if (row < M) {
                Ch[(size_t)row * HROW + col] = __float2half(v);
                st_s1 += v;
                st_q1 += v * v;
            }
        }
    }
    // zero-pad Ch cols 112..127
    if (t < 128) {
        int row = r0 + (t >> 1), o = (t & 1) * 8;
        if (row < M) *(uint4*)((unsigned short*)Ch + (size_t)row * HROW + 112 + o) = make_uint4(0, 0, 0, 0);
    }
    st_s0 += __shfl_xor(st_s0, 16); st_s0 += __shfl_xor(st_s0, 32);
    st_q0 += __shfl_xor(st_q0, 16); st_q0 += __shfl_xor(st_q0, 32);
    st_s1 += __shfl_xor(st_s1, 16); st_s1 += __shfl_xor(st_s1, 32);
    st_q1 += __shfl_xor(st_q1, 16); st_q1 += __shfl_xor(st_q1, 32);
    if (quad == 0) {
        sls[rg * 2 * N + nt0 * 16 + m] = st_s0;
        sls[rg * 2 * N + N + nt0 * 16 + m] = st_q0;
        if (has1) {
            sls[rg * 2 * N + nt1 * 16 + m] = st_s1;
            sls[rg * 2 * N + N + nt1 * 16 + m] = st_q1;
        }
    }
    __syncthreads();
    if (t < 2 * N) {
        pbuf[(size_t)blockIdx.x * 2 * N + t] = sls[0 * 2 * N + t] + sls[1 * 2 * N + t] +
                                               sls[2 * 2 * N + t] + sls[3 * 2 * N + t];
    }
}

// ------- MERGED BN1 finalize + W3 fold (+ zero y sentinel row)
__global__ __launch_bounds__(256) void bn1_w3(const float* __restrict__ pbuf,
                                              const float* __restrict__ gg,
                                              const float* __restrict__ bb,
                                              const float* __restrict__ W,  // g2_w1 [112][32]
                                              unsigned short* __restrict__ w3h,
                                              unsigned short* __restrict__ w3l,
                                              float* __restrict__ c0,
                                              __half* __restrict__ ysent, int M) {
    __shared__ double red[256];
    __shared__ float sv[2];
    int j = blockIdx.x;
    int t = threadIdx.x;
    if (j == 0 && t >= 64 && t < 96) ysent[t - 64] = __float2half(0.f);
    double sum = 0.0, sq = 0.0;
    for (int i = t; i < GEMM_MB; i += 256) {
        sum += (double)pbuf[(size_t)i * 2 * F_IN + j];
        sq  += (double)pbuf[(size_t)i * 2 * F_IN + F_IN + j];
    }
    red[t] = sum;
    __syncthreads();
    for (int o = 128; o > 0; o >>= 1) { if (t < o) red[t] += red[t + o]; __syncthreads(); }
    double total_sum = red[0];
    __syncthreads();
    red[t] = sq;
    __syncthreads();
    for (int o = 128; o > 0; o >>= 1) { if (t < o) red[t] += red[t + o]; __syncthreads(); }
    if (t == 0) {
        double mean = total_sum / M;
        double var = red[0] / M - mean * mean;
        double sc = (double)gg[j] / sqrt(var + BN_EPS);
        sv[0] = (float)sc;
        sv[1] = (float)((double)bb[j] - mean * sc);
    }
    __syncthreads();
    if (t < DIM) {
        float w = W[(size_t)j * DIM + t];
        float v = sv[0] * w;
        unsigned short h = f2h_u(v);
        w3h[t * 128 + j] = h;
        w3l[t * 128 + j] = f2h_u(v - h2f_u(h));
        atomicAdd(&c0[t], sv[1] * w);
    }
}

// ---------- fp16 MFMA GEMM (pure): Ch = A_f16 @ W, W fp16 hi+lo, padded LDS
template <int NT, int KC, int ASG, int CHS>
__global__ __launch_bounds__(256) void gemm_mfma_h(const unsigned short* __restrict__ A,
                                                   const unsigned short* __restrict__ Whi,
                                                   const unsigned short* __restrict__ Wlo,
                                                   __half* __restrict__ Ch, int M) {
    constexpr int N = NT * 16;
    constexpr int Kpad = KC * 32;
    __shared__ __align__(16) unsigned short Ah[64 * WS];
    __shared__ __align__(16) unsigned short Wh[N * WS];
    __shared__ __align__(16) unsigned short Wl[N * WS];
    int t = threadIdx.x;
    int lane = t & 63, wid = t >> 6;
    int r0 = blockIdx.x * 64;
    int m = lane & 15, quad = lane >> 4;

    float4v acc[NT];
#pragma unroll
    for (int nt = 0; nt < NT; nt++) acc[nt] = (float4v){0.f, 0.f, 0.f, 0.f};

    for (int c = 0; c < KC; c++) {
        int kc = c * 32;
        {
            int row = t >> 2, seg = t & 3;
            int grow = r0 + row;
            uint4 v = make_uint4(0, 0, 0, 0);
            if (grow < M) v = *(const uint4*)(A + (size_t)grow * ASG + kc + seg * 8);
            *(uint4*)&Ah[row * WS + seg * 8] = v;
        }
        for (int idx = t; idx < N * 8; idx += 256) {
            int n = idx >> 3, w = idx & 7;
            int gsrc = n * (Kpad / 4) + (kc >> 2) + w;
            ((uint2*)&Wh[n * WS])[w] = ((const uint2*)Whi)[gsrc];
            ((uint2*)&Wl[n * WS])[w] = ((const uint2*)Wlo)[gsrc];
        }
        __syncthreads();
        half8 a = *(const half8*)&Ah[(wid * 16 + m) * WS + quad * 8];
#pragma unroll
        for (int nt = 0; nt < NT; nt++) {
            half8 b_h = *(const half8*)&Wh[(nt * 16 + m) * WS + quad * 8];
            half8 b_l = *(const half8*)&Wl[(nt * 16 + m) * WS + quad * 8];
            acc[nt] = __builtin_amdgcn_mfma_f32_16x16x32_f16(a, b_h, acc[nt], 0, 0, 0);
            acc[nt] = __builtin_amdgcn_mfma_f32_16x16x32_f16(a, b_l, acc[nt], 0, 0, 0);
        }
        __syncthreads();
    }
#pragma unroll
    for (int nt = 0; nt < NT; nt++) {
        int col = nt * 16 + m;
#pragma unroll
        for (int r = 0; r < 4; r++) {
            int row = r0 + wid * 16 + quad * 4 + r;
            if (row < M) Ch[(size_t)row * CHS + col] = __float2half(acc[nt][r]);
        }
    }
}

// ------- FUSED GIN layer 2 (512 thr, 4 blocks/CU = 32 waves/CU):
// 16B-lane gather of y rows (+self+c0+b1+relu) -> H2 = relu(S@W4+b2) + BN2 stats
__global__ __launch_bounds__(512, 8) void gin2_fused(const __half* __restrict__ Y,
        const int* __restrict__ deg_arr,
        const unsigned short* __restrict__ perm_pad,
        const float* __restrict__ c0, const float* __restrict__ cb1,
        const unsigned short* __restrict__ W4h, const unsigned short* __restrict__ W4l,
        const float* __restrict__ bias,
        float* __restrict__ C, float* __restrict__ pbuf, int M) {
    constexpr int N = 32;
    __shared__ __align__(16) unsigned short As[64 * WS];
    __shared__ __align__(16) unsigned short Wh[N * WS];
    __shared__ __align__(16) unsigned short Wl[N * WS];
    __shared__ float sls[4][2 * N];
    int t = threadIdx.x;
    int lane = t & 63, wid = t >> 6;   // 8 waves
    int r0 = blockIdx.x * 64;
    int m = lane & 15, quad = lane >> 4;
    int rg = wid & 3, nt = wid >> 2;   // nt in {0,1}

    // stage W4 under the gather
    for (int idx = t; idx < N * 8; idx += 512) {
        int n = idx >> 3, w = idx & 7;
        int gsrc = n * 8 + w;
        ((uint2*)&Wh[n * WS])[w] = ((const uint2*)W4h)[gsrc];
        ((uint2*)&Wl[n * WS])[w] = ((const uint2*)W4l)[gsrc];
    }

    // gather: lane = (eg 0..15 edge stripes) x (seg 0..3 16B segments)
    int seg = lane & 3, eg = lane >> 2;
#pragma unroll 1
    for (int i = 0; i < 8; i++) {
        int row = wid * 8 + i;
        int grow = r0 + row;
        float ax[8] = {0.f, 0.f, 0.f, 0.f, 0.f, 0.f, 0.f, 0.f};
        int deg = 0;
        if (grow < M) {
            deg = deg_arr[grow];
            const unsigned short* pl = perm_pad + (size_t)grow * CAP;
            int nb = (deg + 15) >> 4;   // batches of 16 edges
#pragma unroll 1
            for (int b = 0; b < nb; b += 2) {   // sentinel-padded
                int s0 = pl[(b + 0) * 16 + eg];
                int s1 = pl[(b + 1) * 16 + eg];
                uint4 u0 = *(const uint4*)(Y + (size_t)s0 * DIM + seg * 8);
                uint4 u1 = *(const uint4*)(Y + (size_t)s1 * DIM + seg * 8);
                acc8(u0, ax); acc8(u1, ax);
            }
        }
#pragma unroll
        for (int p = 0; p < 8; p++) {
            ax[p] += __shfl_xor(ax[p], 4);
            ax[p] += __shfl_xor(ax[p], 8);
            ax[p] += __shfl_xor(ax[p], 16);
            ax[p] += __shfl_xor(ax[p], 32);
        }
        if (eg == 0) {
            uint4 o = make_uint4(0, 0, 0, 0);
            if (grow < M) {
                uint4 sv = *(const uint4*)(Y + (size_t)grow * DIM + seg * 8);
                float deg1 = (float)(deg + 1);
                const __half2* sh = (const __half2*)&sv;
                __half2* oh = (__half2*)&o;
#pragma unroll
                for (int p = 0; p < 4; p++) {
                    float2 sf = __half22float2(sh[p]);
                    int f0 = seg * 8 + 2 * p;
                    float zx = fmaxf(sf.x + ax[2 * p] + deg1 * c0[f0] + cb1[f0], 0.f);
                    float zy = fmaxf(sf.y + ax[2 * p + 1] + deg1 * c0[f0 + 1] + cb1[f0 + 1], 0.f);
                    oh[p] = __floats2half2_rn(zx, zy);
                }
            }
            *(uint4*)&As[row * WS + seg * 8] = o;
        }
    }
    __syncthreads();

    float4v acc = {0.f, 0.f, 0.f, 0.f};
    half8 a = *(const half8*)&As[(rg * 16 + m) * WS + quad * 8];
    half8 bh = *(const half8*)&Wh[(nt * 16 + m) * WS + quad * 8];
    half8 bl = *(const half8*)&Wl[(nt * 16 + m) * WS + quad * 8];
    acc = __builtin_amdgcn_mfma_f32_16x16x32_f16(a, bh, acc, 0, 0, 0);
    acc = __builtin_amdgcn_mfma_f32_16x16x32_f16(a, bl, acc, 0, 0, 0);

    int col = nt * 16 + m;
    float b = bias[col];
    float s_loc = 0.f, q_loc = 0.f;
#pragma unroll
    for (int r = 0; r < 4; r++) {
        int row = r0 + rg * 16 + quad * 4 + r;
        float v = fmaxf(acc[r] + b, 0.f);
        if (row < M) {
            C[(size_t)row * N + col] = v;
            s_loc += v;
            q_loc += v * v;
        }
    }
    s_loc += __shfl_xor(s_loc, 16); s_loc += __shfl_xor(s_loc, 32);
    q_loc += __shfl_xor(q_loc, 16); q_loc += __shfl_xor(q_loc, 32);
    if (quad == 0) {
        sls[rg][col] = s_loc;
        sls[rg][N + col] = q_loc;
    }
    __syncthreads();
    if (t < 2 * N) {
        pbuf[(size_t)blockIdx.x * 2 * N + t] = sls[0][t] + sls[1][t] + sls[2][t] + sls[3][t];
    }
}

// --------- parallel BN finalize
template <int F, int BLOCKS>
__global__ __launch_bounds__(256) void bn_finalize_par(const float* __restrict__ pbuf,
                                                       const float* __restrict__ g,
                                                       const float* __restrict__ b,
                                                       float* __restrict__ s,
                                                       float* __restrict__ tt, int M) {
    __shared__ double red[256];
    int j = blockIdx.x;
    int t = threadIdx.x;
    double sum = 0.0, sq = 0.0;
    for (int i = t; i < BLOCKS; i += 256) {
        sum += (double)pbuf[(size_t)i * 2 * F + j];
        sq  += (double)pbuf[(size_t)i * 2 * F + F + j];
    }
    red[t] = sum;
    __syncthreads();
    for (int o = 128; o > 0; o >>= 1) { if (t < o) red[t] += red[t + o]; __syncthreads(); }
    double total_sum = red[0];
    __syncthreads();
    red[t] = sq;
    __syncthreads();
    for (int o = 128; o > 0; o >>= 1) { if (t < o) red[t] += red[t + o]; __syncthreads(); }
    if (t == 0) {
        double mean = total_sum / M;
        double var = red[0] / M - mean * mean;
        double sc = (double)g[j] / sqrt(var + BN_EPS);
        s[j] = (float)sc;
        tt[j] = (float)((double)b[j] - mean * sc);
    }
}

// -------------------------------------------- pool (BN2 folded) + head
__global__ __launch_bounds__(256) void pool_head(const float* __restrict__ H2, const int* __restrict__ goff,
                                                 const float* __restrict__ s2, const float* __restrict__ t2,
                                                 const float* __restrict__ fcxd_w, const float* __restrict__ fcxd_b,
                                                 const float* __restrict__ fc1_w, const float* __restrict__ fc1_b,
                                                 const float* __restrict__ fc2_w, const float* __restrict__ fc2_b,
                                                 const float* __restrict__ fc3_w, const float* __restrict__ fc3_b,
                                                 const float* __restrict__ fc4_w, const float* __restrict__ fc4_b,
                                                 const float* __restrict__ fc5_w, const float* __restrict__ fc5_b,
                                                 float* __restrict__ out) {
    __shared__ float red[256];
    __shared__ float p[64];
    __shared__ float z[64];
    int g = blockIdx.x, t = threadIdx.x;
    int r0 = goff[g], r1 = goff[g + 1];
    int cnt = r1 - r0;
    int j = t & 31, rr = t >> 5;
    float a = 0.f;
    for (int r = r0 + rr; r < r1; r += 8) a += H2[(size_t)r * DIM + j];
    red[t] = a;
    __syncthreads();
    if (t < 32) {
        float ssum = 0.f;
        for (int q = 0; q < 8; q++) ssum += red[q * 32 + j];
        p[j] = s2[j] * ssum + (float)cnt * t2[j];
    }
    __syncthreads();
    if (t < 64) {
        float acc = fcxd_b[t];
        for (int i = 0; i < 32; i++) acc += p[i] * fcxd_w[i * 64 + t];
        z[t] = fmaxf(acc, 0.f);
    }
    __syncthreads();
    if (t < 32) {
        float acc = fc1_b[t];
        for (int i = 0; i < 64; i++) acc += z[i] * fc1_w[i * 32 + t];
        p[t] = acc;
    }
    __syncthreads();
    if (t < 16) {
        float acc = fc2_b[t];
        for (int i = 0; i < 32; i++) acc += p[i] * fc2_w[i * 16 + t];
        z[t] = acc;
    }
    __syncthreads();
    if (t < 8) {
        float acc = fc3_b[t];
        for (int i = 0; i < 16; i++) acc += z[i] * fc3_w[i * 8 + t];
        p[t] = acc;
    }
    __syncthreads();
    if (t < 2) {
        float acc = fc4_b[t];
        for (int i = 0; i < 8; i++) acc += p[i] * fc4_w[i * 2 + t];
        z[t] = acc;
    }
    __syncthreads();
    if (t == 0) {
        out[g] = z[0] * fc5_w[0] + z[1] * fc5_w[1] + fc5_b[0];
    }
}

// ---------------------------------------------------------------- launch
extern "C" void kernel_launch(void* const* d_in, const int* in_sizes, int n_in,
                              void* d_out, int out_size, void* d_ws, size_t ws_size,
                              hipStream_t stream) {
    const float* x     = (const float*)d_in[0];
    const int*   src   = (const int*)d_in[1];
    const int*   dst   = (const int*)d_in[2];
    const int*   batch = (const int*)d_in[3];
    const float* g1_w1 = (const float*)d_in[4];
    const float* g1_b1 = (const float*)d_in[5];
    const float* g1_w2 = (const float*)d_in[6];
    const float* g1_b2 = (const float*)d_in[7];
    const float* bn1_g = (const float*)d_in[8];
    const float* bn1_b = (const float*)d_in[9];
    const float* g2_w1 = (const float*)d_in[10];
    const float* g2_b1 = (const float*)d_in[11];
    const float* g2_w2 = (const float*)d_in[12];
    const float* g2_b2 = (const float*)d_in[13];
    const float* bn2_g = (const float*)d_in[14];
    const float* bn2_b = (const float*)d_in[15];
    const float* fcxd_w = (const float*)d_in[16];
    const float* fcxd_b = (const float*)d_in[17];
    const float* fc1_w = (const float*)d_in[18];
    const float* fc1_b = (const float*)d_in[19];
    const float* fc2_w = (const float*)d_in[20];
    const float* fc2_b = (const float*)d_in[21];
    const float* fc3_w = (const float*)d_in[22];
    const float* fc3_b = (const float*)d_in[23];
    const float* fc4_w = (const float*)d_in[24];
    const float* fc4_b = (const float*)d_in[25];
    const float* fc5_w = (const float*)d_in[26];
    const float* fc5_b = (const float*)d_in[27];
    float* out = (float*)d_out;
    char* ws = (char*)d_ws;

    size_t off = 0;
    auto take = [&](size_t bytes) { size_t o = off; off += (bytes + 255) & ~(size_t)255; return o; };
    // ---- zeroed region: gcur + c0 + w3 hi/lo (pad rows k>=112 must be 0)
    int* gcur      = (int*)(ws + take((size_t)CB * 4));
    float* c0      = (float*)(ws + take(DIM * 4));
    unsigned short* w3h = (unsigned short*)(ws + take((size_t)DIM * 128 * 2));
    unsigned short* w3l = (unsigned short*)(ws + take((size_t)DIM * 128 * 2));
    size_t zero_bytes = off;
    // ---- rest
    int* bucket    = (int*)(ws + take((size_t)CB * CBCAP * 4));
    unsigned short* perm_pad = (unsigned short*)(ws + take((size_t)N_NODES * CAP * 2));
    int* deg       = (int*)(ws + take((size_t)N_NODES * 4));
    int* goff      = (int*)(ws + take((size_t)(N_GRAPHS + 4) * 4));
    float* s2      = (float*)(ws + take(DIM * 4));
    float* t2      = (float*)(ws + take(DIM * 4));
    float* pb1     = (float*)(ws + take((size_t)GEMM_MB * 2 * F_IN * 4));
    float* pb2     = (float*)(ws + take((size_t)GEMM_MB * 2 * DIM * 4));
    unsigned short* w1h = (unsigned short*)(ws + take((size_t)F_IN * 128 * 2));
    unsigned short* w1l = (unsigned short*)(ws + take((size_t)F_IN * 128 * 2));
    unsigned short* w2h = (unsigned short*)(ws + take((size_t)F_IN * 128 * 2));
    unsigned short* w2l = (unsigned short*)(ws + take((size_t)F_IN * 128 * 2));
    unsigned short* w4h = (unsigned short*)(ws + take((size_t)DIM * 32 * 2));
    unsigned short* w4l = (unsigned short*)(ws + take((size_t)DIM * 32 * 2));
    __half* x_half = (__half*)(ws + take((size_t)(N_NODES + 1) * HROW * 2)); // +1 sentinel row
    __half* h1h    = (__half*)(ws + take((size_t)N_NODES * HROW * 2));
    __half* y_half = (__half*)(ws + take((size_t)(N_NODES + 1) * DIM * 2)); // +1 sentinel row
    float* bufS2   = (float*)(ws + take((size_t)N_NODES * DIM * 4));
    (void)ws_size; (void)in_sizes; (void)n_in; (void)out_size;

    hipMemsetAsync(ws, 0, zero_bytes, stream);

    // graph build: edge partition overlapped with prep in one kernel
    build_kernel<<<MB_GB, 1024, 0, stream>>>(src, dst, gcur, bucket,
                                             x, x_half,
                                             g1_w1, w1h, w1l, g1_w2, w2h, w2l, g2_w2, w4h, w4l,
                                             batch, goff);
    bin_build<<<CB, 1024, 0, stream>>>(gcur, bucket, perm_pad, deg);

    // GIN layer 1: fused gather + MLP (+BN1 stats), then BN1 finalize + W3 fold
    gin1_fused<<<GEMM_MB, 1024, 0, stream>>>(x, x_half, deg, perm_pad,
                                             w1h, w1l, g1_b1, w2h, w2l, g1_b2,
                                             h1h, pb1, N_NODES);
    bn1_w3<<<F_IN, 256, 0, stream>>>(pb1, bn1_g, bn1_b, g2_w1, w3h, w3l, c0,
                                     y_half + (size_t)N_NODES * DIM, N_NODES);

    // GIN layer 2: linear-first (BN1 folded), then fused gather + MLP2 (+BN2 stats)
    gemm_mfma_h<2, 4, HROW, DIM><<<GEMM_MB, 256, 0, stream>>>(
        (const unsigned short*)h1h, w3h, w3l, y_half, N_NODES);
    gin2_fused<<<GEMM_MB, 512, 0, stream>>>(y_half, deg, perm_pad, c0, g2_b1,
                                            w4h, w4l, g2_b2, bufS2, pb2, N_NODES);
    bn_finalize_par<DIM, GEMM_MB><<<DIM, 256, 0, stream>>>(pb2, bn2_g, bn2_b, s2, t2, N_NODES);

    // pool (BN2 folded) + dense head
    pool_head<<<N_GRAPHS, 256, 0, stream>>>(bufS2, goff, s2, t2,
                                            fcxd_w, fcxd_b, fc1_w, fc1_b, fc2_w, fc2_b,
                                            fc3_w, fc3_b, fc4_w, fc4_b, fc5_w, fc5_b, out);
}